// Round 1
// baseline (68.387 us; speedup 1.0000x reference)
//
#include <hip/hip_runtime.h>

// WaveletFeatures: pywt.wavedec(x, 'db4', level=3, mode='symmetric') per row,
// output = concat([cA3, cD3, cD2, cD1]) each flattened row-major.
//
// x: [B=4096, N=8192] fp32. Per-row coeff lengths: M1=4099 (cD1),
// M2=2053 (cD2), M3=1030 (cA3, cD3).  out layout (flat fp32):
//   [0, B*M3)           cA3
//   [B*M3, 2*B*M3)      cD3
//   [2*B*M3, ..+B*M2)   cD2
//   [.., ..+B*M1)       cD1
//
// DWT step (verified against reference's pad+conv composition):
//   y[m] = sum_{s=0..7} f[s] * x_ext[2m+1-s]
// with symmetric (edge-repeating) extension: o<0 -> -1-o ; o>=n -> 2n-1-o.

constexpr int N0 = 8192;
constexpr int M1 = 4099;  // floor((8192+7)/2)
constexpr int M2 = 2053;  // floor((4099+7)/2)
constexpr int M3 = 1030;  // floor((2053+7)/2)
constexpr int NT = 256;

__device__ __forceinline__ int symidx(int o, int n) {
    // single reflection is enough: |overhang| <= 6 << n
    if (o < 0) o = -1 - o;
    if (o >= n) o = 2 * n - 1 - o;
    return o;
}

__device__ __forceinline__ void dwt_step(const float* __restrict__ in, int n,
                                         float* __restrict__ cA,
                                         float* __restrict__ cD, int m) {
    constexpr float LO[8] = {
        -0.010597401784997278f, 0.032883011666982945f, 0.030841381835986965f,
        -0.18703481171888114f,  -0.02798376941698385f, 0.6308807679295904f,
        0.7148465705525415f,    0.23037781330885523f};
    constexpr float HI[8] = {
        -0.23037781330885523f,  0.7148465705525415f,   -0.6308807679295904f,
        -0.02798376941698385f,  0.18703481171888114f,  0.030841381835986965f,
        -0.032883011666982945f, -0.010597401784997278f};
    for (int i = threadIdx.x; i < m; i += NT) {
        const int base = 2 * i + 1;
        float a = 0.f, d = 0.f;
#pragma unroll
        for (int s = 0; s < 8; ++s) {
            const float v = in[symidx(base - s, n)];
            a = fmaf(v, LO[s], a);
            d = fmaf(v, HI[s], d);
        }
        cA[i] = a;
        cD[i] = d;
    }
}

__global__ __launch_bounds__(NT) void WaveletFeatures_77214922047612_kernel(
    const float* __restrict__ x, float* __restrict__ out, int B) {
    __shared__ float sA[N0];  // row, then reused for cA2
    __shared__ float sB[M1];  // cA1
    const int row = blockIdx.x;
    const float* xr = x + (size_t)row * N0;

    // coalesced float4 row load -> LDS
    for (int i = threadIdx.x; i < N0 / 4; i += NT)
        reinterpret_cast<float4*>(sA)[i] =
            reinterpret_cast<const float4*>(xr)[i];
    __syncthreads();

    const size_t cd3_off = (size_t)B * M3;
    const size_t cd2_off = 2 * (size_t)B * M3;
    const size_t cd1_off = (size_t)B * (2 * M3 + M2);

    // level 1: sA[8192] -> cA1 in sB, cD1 -> global
    dwt_step(sA, N0, sB, out + cd1_off + (size_t)row * M1, M1);
    __syncthreads();
    // level 2: sB[4099] -> cA2 in sA (ping-pong), cD2 -> global
    dwt_step(sB, M1, sA, out + cd2_off + (size_t)row * M2, M2);
    __syncthreads();
    // level 3: sA[2053] -> cA3, cD3 -> global
    dwt_step(sA, M2, out + (size_t)row * M3, out + cd3_off + (size_t)row * M3,
             M3);
}

extern "C" void kernel_launch(void* const* d_in, const int* in_sizes, int n_in,
                              void* d_out, int out_size, void* d_ws,
                              size_t ws_size, hipStream_t stream) {
    const float* x = (const float*)d_in[0];
    float* out = (float*)d_out;
    const int B = in_sizes[0] / N0;  // 4096
    WaveletFeatures_77214922047612_kernel<<<dim3(B), dim3(NT), 0, stream>>>(
        x, out, B);
}

// Round 2
// 47.487 us; speedup vs baseline: 1.4401x; 1.4401x over previous
//
#include <hip/hip_runtime.h>

// WaveletFeatures: pywt.wavedec(x, 'db4', level=3, mode='symmetric') per row.
// out = concat([cA3, cD3, cD2, cD1]), each [B, Mk] row-major, flat fp32.
// y[m] = sum_{s=0..7} f[s] * x_sym[2m+1-s];  sym: o<0 -> -1-o ; o>=n -> 2n-1-o.
//
// R2 design: no row staging (level 1 reads global directly, L1 absorbs the 2x
// overlap); LDS holds only cA1 (16.4KB) + cA2 (8.2KB) -> 6 blocks/CU.
// Interior computed in chunks of 4 outputs from an aligned 16-float register
// window (4x dwordx4 / ds_read_b128); only the few edge outputs use symidx.

constexpr int N0 = 8192;
constexpr int M1 = 4099;  // floor((8192+7)/2)
constexpr int M2 = 2053;
constexpr int M3 = 1030;
constexpr int NT = 256;

// fast-chunk counts: i0 = 4 + 4c, window [2*i0-8, 2*i0+7] fully interior
constexpr int C1 = 1023;  // i0 in [4, 4092], covers outputs 4..4095
constexpr int C2 = 511;   // i0 in [4, 2044], covers 4..2047
constexpr int C3 = 255;   // i0 in [4, 1020], covers 4..1023

__device__ __forceinline__ int symidx(int o, int n) {
    if (o < 0) o = -1 - o;
    if (o >= n) o = 2 * n - 1 - o;  // single reflection suffices (overhang<=6)
    return o;
}

// 4 output pairs from window w[k] = in[2*i0 - 8 + k], k=0..15.
// y[i0+j] = sum_t RF[t] * w[2j+2+t], RF = reversed filter.
__device__ __forceinline__ void compute4(const float* __restrict__ w,
                                         float* __restrict__ a,
                                         float* __restrict__ d) {
    constexpr float RLO[8] = {0.23037781330885523f,  0.7148465705525415f,
                              0.6308807679295904f,   -0.02798376941698385f,
                              -0.18703481171888114f, 0.030841381835986965f,
                              0.032883011666982945f, -0.010597401784997278f};
    constexpr float RHI[8] = {-0.010597401784997278f, -0.032883011666982945f,
                              0.030841381835986965f,  0.18703481171888114f,
                              -0.02798376941698385f,  -0.6308807679295904f,
                              0.7148465705525415f,    -0.23037781330885523f};
#pragma unroll
    for (int j = 0; j < 4; ++j) {
        float aj = 0.f, dj = 0.f;
#pragma unroll
        for (int t = 0; t < 8; ++t) {
            const float v = w[2 * j + 2 + t];
            aj = fmaf(RLO[t], v, aj);
            dj = fmaf(RHI[t], v, dj);
        }
        a[j] = aj;
        d[j] = dj;
    }
}

__device__ __forceinline__ void edge_pair(const float* in, int n, int i,
                                          float& a, float& d) {
    constexpr float LO[8] = {
        -0.010597401784997278f, 0.032883011666982945f, 0.030841381835986965f,
        -0.18703481171888114f,  -0.02798376941698385f, 0.6308807679295904f,
        0.7148465705525415f,    0.23037781330885523f};
    constexpr float HI[8] = {
        -0.23037781330885523f,  0.7148465705525415f,   -0.6308807679295904f,
        -0.02798376941698385f,  0.18703481171888114f,  0.030841381835986965f,
        -0.032883011666982945f, -0.010597401784997278f};
    a = 0.f;
    d = 0.f;
#pragma unroll
    for (int s = 0; s < 8; ++s) {
        const float v = in[symidx(2 * i + 1 - s, n)];
        a = fmaf(LO[s], v, a);
        d = fmaf(HI[s], v, d);
    }
}

__global__ __launch_bounds__(NT) void WaveletFeatures_77214922047612_kernel(
    const float* __restrict__ x, float* __restrict__ out, int B) {
    __shared__ __align__(16) float s1[M1 + 1];  // cA1
    __shared__ __align__(16) float s2[M2 + 3];  // cA2

    const int row = blockIdx.x;
    const int tid = threadIdx.x;
    const float* xr = x + (size_t)row * N0;

    float* ca3 = out + (size_t)row * M3;
    float* cd3 = out + (size_t)B * M3 + (size_t)row * M3;
    float* cd2 = out + 2 * (size_t)B * M3 + (size_t)row * M2;
    float* cd1 = out + (size_t)B * (2 * M3 + M2) + (size_t)row * M1;

    // ---------- level 1: x (global, n=8192) -> cA1 in s1, cD1 -> global ----
    for (int c = tid; c < C1; c += NT) {
        const int i0 = 4 + 4 * c;
        float w[16];
        const float4* p = reinterpret_cast<const float4*>(xr + 2 * i0 - 8);
        *reinterpret_cast<float4*>(&w[0]) = p[0];
        *reinterpret_cast<float4*>(&w[4]) = p[1];
        *reinterpret_cast<float4*>(&w[8]) = p[2];
        *reinterpret_cast<float4*>(&w[12]) = p[3];
        float a[4], d[4];
        compute4(w, a, d);
        *reinterpret_cast<float4*>(&s1[i0]) = make_float4(a[0], a[1], a[2], a[3]);
        cd1[i0 + 0] = d[0];
        cd1[i0 + 1] = d[1];
        cd1[i0 + 2] = d[2];
        cd1[i0 + 3] = d[3];
    }
    if (tid < 7) {  // edges: {0,1,2,3, 4096,4097,4098}
        const int i = tid < 4 ? tid : 4092 + tid;
        float a, d;
        edge_pair(xr, N0, i, a, d);
        s1[i] = a;
        cd1[i] = d;
    }
    __syncthreads();

    // ---------- level 2: s1 (n=4099) -> cA2 in s2, cD2 -> global ----------
    for (int c = tid; c < C2; c += NT) {
        const int i0 = 4 + 4 * c;
        float w[16];
        const float4* p = reinterpret_cast<const float4*>(&s1[2 * i0 - 8]);
        *reinterpret_cast<float4*>(&w[0]) = p[0];
        *reinterpret_cast<float4*>(&w[4]) = p[1];
        *reinterpret_cast<float4*>(&w[8]) = p[2];
        *reinterpret_cast<float4*>(&w[12]) = p[3];
        float a[4], d[4];
        compute4(w, a, d);
        *reinterpret_cast<float4*>(&s2[i0]) = make_float4(a[0], a[1], a[2], a[3]);
        cd2[i0 + 0] = d[0];
        cd2[i0 + 1] = d[1];
        cd2[i0 + 2] = d[2];
        cd2[i0 + 3] = d[3];
    }
    if (tid < 9) {  // edges: {0..3, 2048..2052}
        const int i = tid < 4 ? tid : 2044 + tid;
        float a, d;
        edge_pair(s1, M1, i, a, d);
        s2[i] = a;
        cd2[i] = d;
    }
    __syncthreads();

    // ---------- level 3: s2 (n=2053) -> cA3, cD3 -> global ----------------
    for (int c = tid; c < C3; c += NT) {
        const int i0 = 4 + 4 * c;
        float w[16];
        const float4* p = reinterpret_cast<const float4*>(&s2[2 * i0 - 8]);
        *reinterpret_cast<float4*>(&w[0]) = p[0];
        *reinterpret_cast<float4*>(&w[4]) = p[1];
        *reinterpret_cast<float4*>(&w[8]) = p[2];
        *reinterpret_cast<float4*>(&w[12]) = p[3];
        float a[4], d[4];
        compute4(w, a, d);
#pragma unroll
        for (int j = 0; j < 4; ++j) {
            ca3[i0 + j] = a[j];
            cd3[i0 + j] = d[j];
        }
    }
    if (tid < 10) {  // edges: {0..3, 1024..1029}
        const int i = tid < 4 ? tid : 1020 + tid;
        float a, d;
        edge_pair(s2, M2, i, a, d);
        ca3[i] = a;
        cd3[i] = d;
    }
}

extern "C" void kernel_launch(void* const* d_in, const int* in_sizes, int n_in,
                              void* d_out, int out_size, void* d_ws,
                              size_t ws_size, hipStream_t stream) {
    const float* x = (const float*)d_in[0];
    float* out = (float*)d_out;
    const int B = in_sizes[0] / N0;  // 4096
    WaveletFeatures_77214922047612_kernel<<<dim3(B), dim3(NT), 0, stream>>>(
        x, out, B);
}